// Round 1
// baseline (382.340 us; speedup 1.0000x reference)
//
#include <hip/hip_runtime.h>

#define SEQS_PER_WG 16
#define HID 128
#define NF 13
#define SLEN 128
#define NSEQ 2048
#define ZSTRIDE 232   // f16 elems per z row; 232*2=464B (16B-aligned rows, bank-friendly: 116%32=20)

typedef _Float16 half8 __attribute__((ext_vector_type(8)));
typedef float floatx4 __attribute__((ext_vector_type(4)));

__device__ __forceinline__ float fast_rcp(float x) { return __builtin_amdgcn_rcpf(x); }
__device__ __forceinline__ float sigm(float x)  { return fast_rcp(1.0f + __expf(-x)); }
__device__ __forceinline__ float tanh_(float x) { return 1.0f - 2.0f * fast_rcp(1.0f + __expf(2.0f * x)); }

__global__ __launch_bounds__(256, 1)
void lstm_encdec_kernel(const float* __restrict__ X,
                        const float* __restrict__ W_ih,
                        const float* __restrict__ W_hh,
                        const float* __restrict__ b_ih,
                        const float* __restrict__ b_hh,
                        const float* __restrict__ W_fc,
                        const float* __restrict__ b_fc,
                        float* __restrict__ out)
{
    // z = [h (128) | x (13, padded to 32 with zeros)] per sequence, fp16, double-buffered
    __shared__ _Float16 zbuf[2][SEQS_PER_WG * ZSTRIDE];

    const int tid  = threadIdx.x;
    const int wave = tid >> 6;
    const int lane = tid & 63;
    const int quad = lane >> 4;
    const int lcol = lane & 15;       // MFMA C/D col, A/B "m/n" index
    const int lrow = quad * 4;        // MFMA C/D row base (rows lrow..lrow+3)
    const int seq0 = blockIdx.x * SEQS_PER_WG;

    // ---- preload loop-invariant B fragments: 4 gate groups x 2 col-subtiles x 5 K-steps ----
    // gates[s][n] = sum_k z[s][k] * W[n][k];  n = g*128 + wave*32 + sub*16 + lcol
    half8 Bf[4][2][5];
    float bias[4][2];
    #pragma unroll
    for (int g = 0; g < 4; ++g) {
        #pragma unroll
        for (int sub = 0; sub < 2; ++sub) {
            const int n = g * 128 + wave * 32 + sub * 16 + lcol;
            #pragma unroll
            for (int ks = 0; ks < 4; ++ks) {            // h part: W_hh[n][ks*32 + quad*8 + j]
                const float* p = W_hh + n * HID + ks * 32 + quad * 8;
                half8 v;
                #pragma unroll
                for (int j = 0; j < 8; ++j) v[j] = (_Float16)p[j];
                Bf[g][sub][ks] = v;
            }
            {   // x part (K-step 4): W_ih[n][kk] for kk<13 else 0
                half8 v;
                #pragma unroll
                for (int j = 0; j < 8; ++j) {
                    int kk = quad * 8 + j;
                    v[j] = (kk < NF) ? (_Float16)W_ih[n * NF + kk] : (_Float16)0.0f;
                }
                Bf[g][sub][4] = v;
            }
            bias[g][sub] = b_ih[n] + b_hh[n];
        }
    }

    // W_fc fragments (wave 0 only): out[s][f] = sum_k h[s][k] * W_fc[f][k] + b_fc[f]
    half8 Wfcf[4];
    float bfc = 0.0f;
    if (wave == 0) {
        #pragma unroll
        for (int ks = 0; ks < 4; ++ks) {
            half8 v;
            #pragma unroll
            for (int j = 0; j < 8; ++j)
                v[j] = (lcol < NF) ? (_Float16)W_fc[lcol * HID + ks * 32 + quad * 8 + j]
                                   : (_Float16)0.0f;
            Wfcf[ks] = v;
        }
        if (lcol < NF) bfc = b_fc[lcol];
    }

    // ---- init LDS: zero both buffers (h=0, pad=0), then x_0 ----
    for (int i = tid; i < 2 * SEQS_PER_WG * ZSTRIDE; i += 256)
        ((_Float16*)zbuf)[i] = (_Float16)0.0f;
    __syncthreads();
    if (tid < SEQS_PER_WG * NF) {
        int s = tid / NF, f = tid % NF;
        zbuf[0][s * ZSTRIDE + HID + f] = (_Float16)X[(seq0 + s) * SLEN * NF + f];
    }
    __syncthreads();

    float creg[2][4];
    #pragma unroll
    for (int i = 0; i < 2; ++i)
        #pragma unroll
        for (int r = 0; r < 4; ++r) creg[i][r] = 0.0f;
    float hreg[2][4];

    int p = 0;

    // ===================== encoder: 128 steps, 1 barrier/step =====================
    for (int t = 0; t < SLEN; ++t) {
        // prefetch next x into register early (hide global latency behind compute)
        const int tn = (t + 1 < SLEN) ? t + 1 : SLEN - 1;
        float xpre = 0.0f;
        int xs = 0, xf = 0;
        if (tid < SEQS_PER_WG * NF) {
            xs = tid / NF; xf = tid % NF;
            xpre = X[(seq0 + xs) * SLEN * NF + tn * NF + xf];
        }

        half8 a[5];
        #pragma unroll
        for (int ks = 0; ks < 5; ++ks)
            a[ks] = *(const half8*)&zbuf[p][lcol * ZSTRIDE + ks * 32 + quad * 8];

        floatx4 acc[4][2];
        #pragma unroll
        for (int g = 0; g < 4; ++g)
            #pragma unroll
            for (int sub = 0; sub < 2; ++sub) {
                float b = bias[g][sub];
                acc[g][sub] = (floatx4){b, b, b, b};
            }
        #pragma unroll
        for (int ks = 0; ks < 5; ++ks)
            #pragma unroll
            for (int g = 0; g < 4; ++g)
                #pragma unroll
                for (int sub = 0; sub < 2; ++sub)
                    acc[g][sub] = __builtin_amdgcn_mfma_f32_16x16x32_f16(
                        a[ks], Bf[g][sub][ks], acc[g][sub], 0, 0, 0);

        #pragma unroll
        for (int sub = 0; sub < 2; ++sub)
            #pragma unroll
            for (int r = 0; r < 4; ++r) {
                float ii = sigm(acc[0][sub][r]);
                float ff = sigm(acc[1][sub][r]);
                float gg = tanh_(acc[2][sub][r]);
                float oo = sigm(acc[3][sub][r]);
                float c  = ff * creg[sub][r] + ii * gg;
                creg[sub][r] = c;
                float h = oo * tanh_(c);
                hreg[sub][r] = h;
                zbuf[1 - p][(lrow + r) * ZSTRIDE + wave * 32 + sub * 16 + lcol] = (_Float16)h;
            }

        if (tid < SEQS_PER_WG * NF)
            zbuf[1 - p][xs * ZSTRIDE + HID + xf] = (_Float16)xpre;

        __syncthreads();
        p ^= 1;
    }

    // embeddings = h_n : out[(seq)*128 + unit]
    #pragma unroll
    for (int sub = 0; sub < 2; ++sub)
        #pragma unroll
        for (int r = 0; r < 4; ++r)
            out[(seq0 + lrow + r) * HID + wave * 32 + sub * 16 + lcol] = hreg[sub][r];

    // ===================== decoder: 128 steps, 2 barriers/step =====================
    float* dec = out + NSEQ * HID;
    for (int t = 0; t < SLEN; ++t) {
        half8 a[5];
        #pragma unroll
        for (int ks = 0; ks < 5; ++ks)
            a[ks] = *(const half8*)&zbuf[p][lcol * ZSTRIDE + ks * 32 + quad * 8];

        floatx4 acc[4][2];
        #pragma unroll
        for (int g = 0; g < 4; ++g)
            #pragma unroll
            for (int sub = 0; sub < 2; ++sub) {
                float b = bias[g][sub];
                acc[g][sub] = (floatx4){b, b, b, b};
            }
        #pragma unroll
        for (int ks = 0; ks < 5; ++ks)
            #pragma unroll
            for (int g = 0; g < 4; ++g)
                #pragma unroll
                for (int sub = 0; sub < 2; ++sub)
                    acc[g][sub] = __builtin_amdgcn_mfma_f32_16x16x32_f16(
                        a[ks], Bf[g][sub][ks], acc[g][sub], 0, 0, 0);

        #pragma unroll
        for (int sub = 0; sub < 2; ++sub)
            #pragma unroll
            for (int r = 0; r < 4; ++r) {
                float ii = sigm(acc[0][sub][r]);
                float ff = sigm(acc[1][sub][r]);
                float gg = tanh_(acc[2][sub][r]);
                float oo = sigm(acc[3][sub][r]);
                float c  = ff * creg[sub][r] + ii * gg;
                creg[sub][r] = c;
                float h = oo * tanh_(c);
                zbuf[1 - p][(lrow + r) * ZSTRIDE + wave * 32 + sub * 16 + lcol] = (_Float16)h;
            }

        __syncthreads();   // h_{t+1} complete in z[1-p]

        if (wave == 0) {
            half8 af[4];
            #pragma unroll
            for (int ks = 0; ks < 4; ++ks)
                af[ks] = *(const half8*)&zbuf[1 - p][lcol * ZSTRIDE + ks * 32 + quad * 8];
            floatx4 o = (floatx4){bfc, bfc, bfc, bfc};
            #pragma unroll
            for (int ks = 0; ks < 4; ++ks)
                o = __builtin_amdgcn_mfma_f32_16x16x32_f16(af[ks], Wfcf[ks], o, 0, 0, 0);
            if (lcol < NF) {
                #pragma unroll
                for (int r = 0; r < 4; ++r) {
                    float v = o[r];
                    dec[(seq0 + lrow + r) * SLEN * NF + t * NF + lcol] = v;
                    zbuf[1 - p][(lrow + r) * ZSTRIDE + HID + lcol] = (_Float16)v;
                }
            }
        }

        __syncthreads();   // out written to z[1-p] x-slot
        p ^= 1;
    }
}

extern "C" void kernel_launch(void* const* d_in, const int* in_sizes, int n_in,
                              void* d_out, int out_size, void* d_ws, size_t ws_size,
                              hipStream_t stream) {
    const float* X    = (const float*)d_in[0];
    const float* W_ih = (const float*)d_in[1];
    const float* W_hh = (const float*)d_in[2];
    const float* b_ih = (const float*)d_in[3];
    const float* b_hh = (const float*)d_in[4];
    const float* W_fc = (const float*)d_in[5];
    const float* b_fc = (const float*)d_in[6];
    float* out = (float*)d_out;

    lstm_encdec_kernel<<<NSEQ / SEQS_PER_WG, 256, 0, stream>>>(
        X, W_ih, W_hh, b_ih, b_hh, W_fc, b_fc, out);
}